// Round 9
// baseline (74.343 us; speedup 1.0000x reference)
//
#include <hip/hip_runtime.h>
#include <math.h>

// SimpleMamba: s_t = A*s_{t-1} + B*x_t ; y_t = tanh(C*s_t), per-channel.
// L=8192, D=2048, f32.
//
// R9: TWO kernels.
//  K1 = phase-1 (per-chunk local end states) + inline carry scan performed by
//       the LAST 4 blocks to finish (atomic ticket; only 4 pollers, others
//       exit -> no R6-style 512-way spin convoy / cross-XCD line ping-pong).
//  K2 = phase-3 (recompute from carry, emit tanh), R7's measured-best geometry
//       (512 blocks x 256 thr), loads/compute/stores clustered in 8-batches.
// Removes the separate p2 dispatch and one kernel boundary vs R7 (48.6 us).
// CL=32 pinned by f32 overflow; p=A^32>0 (even power) keeps inf carries
// sign-stable, loc always finite -> no inf-inf NaN. Flat-serial carry chain
// (tree compose IS inf-inf NaN-unsafe for |A|>1 channels).

#define LL 8192
#define DD 2048
#define CL 32
#define NC (LL / CL)        // 256 chunks
#define G4 (DD / 4)         // 512 float4 channel-groups per row
#define NBLK1 (NC * G4 / 256)  // 512 blocks in K1
#define NFIN 4              // finisher blocks that run the scan

typedef float f32x4 __attribute__((ext_vector_type(4)));

__device__ __forceinline__ float fast_tanh(float z)
{
    // tanh(z) = 1 - 2/(exp2(2z*log2e)+1); exact saturation at +-inf, ~1e-7 err.
    float e = __builtin_amdgcn_exp2f(z * 2.885390081777927f);
    return 1.0f - 2.0f * __builtin_amdgcn_rcpf(e + 1.0f);
}

// ==================== K1: local states + last-4-blocks inline scan ====================
__global__ __launch_bounds__(256) void mamba_k1(
    const float4* __restrict__ x4, const float4* __restrict__ A4,
    const float4* __restrict__ B4, float4* __restrict__ loc4,
    float* __restrict__ car, unsigned* __restrict__ cnt)
{
    const int lin   = blockIdx.x * 256 + threadIdx.x;
    const int chunk = lin >> 9;          // / G4
    const int grp   = lin & (G4 - 1);

    const float4 a = A4[grp];
    const float4 b = B4[grp];

    float sx = 0.f, sy = 0.f, sz = 0.f, sw = 0.f;
    const float4* xp = x4 + (size_t)chunk * CL * G4 + grp;
    #pragma unroll
    for (int t0 = 0; t0 < CL; t0 += 16) {
        float4 v[16];
        #pragma unroll
        for (int k = 0; k < 16; ++k)
            v[k] = xp[(size_t)(t0 + k) * G4];     // 16 dwordx4 in flight
        #pragma unroll
        for (int k = 0; k < 16; ++k) {
            sx = fmaf(a.x, sx, b.x * v[k].x);
            sy = fmaf(a.y, sy, b.y * v[k].y);
            sz = fmaf(a.z, sz, b.z * v[k].z);
            sw = fmaf(a.w, sw, b.w * v[k].w);
        }
    }
    loc4[(size_t)chunk * G4 + grp] = make_float4(sx, sy, sz, sw);

    // ---- ticket: the last NFIN blocks to arrive run the scan; others exit ----
    __shared__ unsigned ticket_s;
    __syncthreads();                          // all lanes' loc stores issued
    if (threadIdx.x == 0) {
        __threadfence();                      // release loc to device scope
        ticket_s = __hip_atomic_fetch_add(&cnt[0], 1u,
                       __ATOMIC_RELAXED, __HIP_MEMORY_SCOPE_AGENT);
    }
    __syncthreads();
    const unsigned ticket = ticket_s;
    if (ticket < NBLK1 - NFIN) return;        // wait-free exit for 508 blocks

    // ---- finisher: wait for all 512 arrivals (<=4 pollers, short wait) ----
    if (threadIdx.x == 0) {
        while (__hip_atomic_load(&cnt[0], __ATOMIC_RELAXED,
                                 __HIP_MEMORY_SCOPE_AGENT) < NBLK1)
            __builtin_amdgcn_s_sleep(1);
        __threadfence();                      // acquire: fresh loc
    }
    __syncthreads();

    // ---- inline scan: this block handles 512 channels (2 per thread) ----
    // carry[c] = state entering chunk c; carry[c+1] = A^32*carry[c] + loc[c].
    const int f  = (int)ticket - (NBLK1 - NFIN);      // 0..3
    const int ch = f * 512 + (int)threadIdx.x * 2;    // even channel index

    float pa = ((const float*)A4)[ch];
    float pb = ((const float*)A4)[ch + 1];
    #pragma unroll
    for (int i = 0; i < 5; ++i) { pa *= pa; pb *= pb; }   // A^32 > 0, finite

    const float2* locv = (const float2*)loc4;
    float2*       carv = (float2*)car;
    const int     colv = ch >> 1;

    float cx = 0.f, cy = 0.f;
    for (int j0 = 0; j0 < NC; j0 += 32) {
        float2 lv[32];
        #pragma unroll
        for (int k = 0; k < 32; ++k)
            lv[k] = locv[(size_t)(j0 + k) * (DD / 2) + colv];  // 32 loads in flight
        #pragma unroll
        for (int k = 0; k < 32; ++k) {
            carv[(size_t)(j0 + k) * (DD / 2) + colv] = make_float2(cx, cy);
            cx = fmaf(pa, cx, lv[k].x);       // lv finite, p>0 -> no inf-inf NaN
            cy = fmaf(pb, cy, lv[k].y);
        }
    }
}

// ==================== K2: recompute from carry, emit tanh(C*s) ====================
__global__ __launch_bounds__(256) void mamba_p3(
    const float4* __restrict__ x4, const float4* __restrict__ A4,
    const float4* __restrict__ B4, const float4* __restrict__ C4,
    const float4* __restrict__ car4, float4* __restrict__ y4)
{
    const int lin   = blockIdx.x * 256 + threadIdx.x;
    const int chunk = lin >> 9;
    const int grp   = lin & (G4 - 1);

    const float4 a = A4[grp];
    const float4 b = B4[grp];
    const float4 c = C4[grp];
    float4 s0 = car4[(size_t)chunk * G4 + grp];
    float sx = s0.x, sy = s0.y, sz = s0.z, sw = s0.w;

    const float4* xp = x4 + (size_t)chunk * CL * G4 + grp;
    float4*       yp = y4 + (size_t)chunk * CL * G4 + grp;

    #pragma unroll
    for (int t0 = 0; t0 < CL; t0 += 8) {
        float4 v[8];
        #pragma unroll
        for (int k = 0; k < 8; ++k)
            v[k] = xp[(size_t)(t0 + k) * G4];     // burst: 8 loads in flight
        f32x4 o[8];
        #pragma unroll
        for (int k = 0; k < 8; ++k) {             // compute phase
            sx = fmaf(a.x, sx, b.x * v[k].x);
            sy = fmaf(a.y, sy, b.y * v[k].y);
            sz = fmaf(a.z, sz, b.z * v[k].z);
            sw = fmaf(a.w, sw, b.w * v[k].w);
            o[k].x = fast_tanh(c.x * sx);
            o[k].y = fast_tanh(c.y * sy);
            o[k].z = fast_tanh(c.z * sz);
            o[k].w = fast_tanh(c.w * sw);
        }
        #pragma unroll
        for (int k = 0; k < 8; ++k)               // burst: 8 stores back-to-back
            __builtin_nontemporal_store(o[k], (f32x4*)&yp[(size_t)(t0 + k) * G4]);
    }
}

extern "C" void kernel_launch(void* const* d_in, const int* in_sizes, int n_in,
                              void* d_out, int out_size, void* d_ws, size_t ws_size,
                              hipStream_t stream)
{
    const float4* x4 = (const float4*)d_in[0];   // [L, D] f32
    const float4* A4 = (const float4*)d_in[1];   // [D]
    const float4* B4 = (const float4*)d_in[2];   // [D]
    const float4* C4 = (const float4*)d_in[3];   // [D]
    float4* y4 = (float4*)d_out;                 // [L, D] f32

    // workspace: loc (2 MiB) + carry (2 MiB) + ticket counter
    float4* loc4 = (float4*)d_ws;
    float*  carf = (float*)d_ws + (size_t)NC * DD;
    float4* car4 = (float4*)carf;
    unsigned* cnt = (unsigned*)((char*)d_ws + (size_t)NC * DD * 4 * 2);

    (void)hipMemsetAsync(cnt, 0, 16, stream);    // ticket counter starts at 0 each call

    mamba_k1<<<NBLK1, 256, 0, stream>>>(x4, A4, B4, loc4, carf, cnt);
    mamba_p3<<<NBLK1, 256, 0, stream>>>(x4, A4, B4, C4, car4, y4);
}

// Round 10
// 58.714 us; speedup vs baseline: 1.2662x; 1.2662x over previous
//
#include <hip/hip_runtime.h>
#include <math.h>

// SimpleMamba: s_t = A*s_{t-1} + B*x_t ; y_t = tanh(C*s_t), per-channel.
// L=8192, D=2048, f32.
//
// R10: 3-kernel chunked scan (fusion attempts R5/R6/R9 all lost to codegen or
// spin-barrier costs; 3-kernel R7 = 48.6 us is the skeleton). Lever this round:
// OCCUPANCY. R7's p1/p3 ran 512 blocks = 2 waves/SIMD -- too few to hide HBM
// latency around the serial per-thread fma chain (p3 measured ~4.4 TB/s eff).
// CL 32->16, NC 256->512: 1024 blocks = 4 blocks/CU = 4 waves/SIMD.
// Numerics: p = A^16 > 0 (even power, finite; max|A|~3.9 -> 2.9e9); chunk-local
// sums <= ~1e11 finite; |A|>1 carries may hit +-inf but stay sign-stable
// (p>0, loc finite -> no inf-inf NaN); tanh saturates to +-1 like the ref.
// Carry chain stays flat-serial (tree compose IS inf-inf NaN-unsafe).

#define LL 8192
#define DD 2048
#define CL 16
#define NC (LL / CL)   // 512 chunks
#define G4 (DD / 4)    // 512 float4 channel-groups per row

typedef float f32x4 __attribute__((ext_vector_type(4)));

__device__ __forceinline__ float fast_tanh(float z)
{
    // tanh(z) = 1 - 2/(exp2(2z*log2e)+1); exact saturation at +-inf, ~1e-7 err.
    float e = __builtin_amdgcn_exp2f(z * 2.885390081777927f);
    return 1.0f - 2.0f * __builtin_amdgcn_rcpf(e + 1.0f);
}

// ---------------- Phase 1: per-chunk local end-state (from s=0) ----------------
// 1024 blocks x 256 thr = 4 blocks/CU = 4 waves/SIMD.
__global__ __launch_bounds__(256) void mamba_p1(
    const float4* __restrict__ x4, const float4* __restrict__ A4,
    const float4* __restrict__ B4, float4* __restrict__ loc4)
{
    int lin   = blockIdx.x * 256 + threadIdx.x;   // NC * G4 threads
    int chunk = lin >> 9;                         // / G4
    int grp   = lin & (G4 - 1);

    float4 a = A4[grp];
    float4 b = B4[grp];
    float sx = 0.f, sy = 0.f, sz = 0.f, sw = 0.f;

    const float4* xp = x4 + (size_t)chunk * CL * G4 + grp;
    float4 v[CL];
    #pragma unroll
    for (int t = 0; t < CL; ++t)
        v[t] = xp[(size_t)t * G4];                // 16 dwordx4 in flight
    #pragma unroll
    for (int t = 0; t < CL; ++t) {
        sx = fmaf(a.x, sx, b.x * v[t].x);
        sy = fmaf(a.y, sy, b.y * v[t].y);
        sz = fmaf(a.z, sz, b.z * v[t].z);
        sw = fmaf(a.w, sw, b.w * v[t].w);
    }
    loc4[(size_t)chunk * G4 + grp] = make_float4(sx, sy, sz, sw);
}

// ---------------- Phase 2: serial scan over chunks, one thread per CHANNEL ----------------
// carry[c] = state entering chunk c; carry[c+1] = A^CL * carry[c] + loc[c].
// 2048 threads over 32 blocks; NC=512 -> 8 batches of 64 loads in flight.
__global__ __launch_bounds__(64) void mamba_p2(
    const float* __restrict__ A, const float* __restrict__ loc,
    float* __restrict__ car)
{
    int ch = blockIdx.x * 64 + threadIdx.x;       // 0..DD-1
    float p = A[ch];
    #pragma unroll
    for (int i = 0; i < 4; ++i) p *= p;           // A^16 > 0, finite

    float c = 0.f;
    for (int c0 = 0; c0 < NC; c0 += 64) {
        float lv[64];
        #pragma unroll
        for (int k = 0; k < 64; ++k)
            lv[k] = loc[(size_t)(c0 + k) * DD + ch];   // 64 loads in flight
        #pragma unroll
        for (int k = 0; k < 64; ++k) {
            car[(size_t)(c0 + k) * DD + ch] = c;
            c = fmaf(p, c, lv[k]);                     // loc finite, p>0: no inf-inf
        }
    }
}

// ---------------- Phase 3: recompute recurrence from carry, emit tanh(C*s) ----------------
// Same geometry as p1; x re-read is L3-warm (proven R6: FETCH stayed ~66 MiB).
__global__ __launch_bounds__(256) void mamba_p3(
    const float4* __restrict__ x4, const float4* __restrict__ A4,
    const float4* __restrict__ B4, const float4* __restrict__ C4,
    const float4* __restrict__ car4, float4* __restrict__ y4)
{
    int lin   = blockIdx.x * 256 + threadIdx.x;
    int chunk = lin >> 9;
    int grp   = lin & (G4 - 1);

    float4 a = A4[grp];
    float4 b = B4[grp];
    float4 c = C4[grp];
    float4 s0 = car4[(size_t)chunk * G4 + grp];
    float sx = s0.x, sy = s0.y, sz = s0.z, sw = s0.w;

    const float4* xp = x4 + (size_t)chunk * CL * G4 + grp;
    float4*       yp = y4 + (size_t)chunk * CL * G4 + grp;

    #pragma unroll
    for (int t0 = 0; t0 < CL; t0 += 8) {
        float4 v[8];
        #pragma unroll
        for (int k = 0; k < 8; ++k)
            v[k] = xp[(size_t)(t0 + k) * G4];     // 8 dwordx4 in flight
        #pragma unroll
        for (int k = 0; k < 8; ++k) {
            sx = fmaf(a.x, sx, b.x * v[k].x);
            sy = fmaf(a.y, sy, b.y * v[k].y);
            sz = fmaf(a.z, sz, b.z * v[k].z);
            sw = fmaf(a.w, sw, b.w * v[k].w);
            f32x4 o;
            o.x = fast_tanh(c.x * sx);
            o.y = fast_tanh(c.y * sy);
            o.z = fast_tanh(c.z * sz);
            o.w = fast_tanh(c.w * sw);
            __builtin_nontemporal_store(o, (f32x4*)&yp[(size_t)(t0 + k) * G4]);
        }
    }
}

extern "C" void kernel_launch(void* const* d_in, const int* in_sizes, int n_in,
                              void* d_out, int out_size, void* d_ws, size_t ws_size,
                              hipStream_t stream)
{
    const float4* x4 = (const float4*)d_in[0];   // [L, D] f32
    const float*  Af = (const float*)d_in[1];
    const float4* A4 = (const float4*)d_in[1];   // [D]
    const float4* B4 = (const float4*)d_in[2];   // [D]
    const float4* C4 = (const float4*)d_in[3];   // [D]
    float4* y4 = (float4*)d_out;                 // [L, D] f32

    // workspace: loc (NC*D f32 = 4 MiB) + carry (4 MiB)
    float*  locf = (float*)d_ws;
    float4* loc4 = (float4*)d_ws;
    float*  carf = locf + (size_t)NC * DD;
    float4* car4 = (float4*)carf;

    const int nthreads = NC * G4;                // 262144
    mamba_p1<<<nthreads / 256, 256, 0, stream>>>(x4, A4, B4, loc4);
    mamba_p2<<<DD / 64, 64, 0, stream>>>(Af, locf, carf);
    mamba_p3<<<nthreads / 256, 256, 0, stream>>>(x4, A4, B4, C4, car4, y4);
}